// Round 18
// baseline (492.207 us; speedup 1.0000x reference)
//
#include <hip/hip_runtime.h>
#include <math.h>

typedef __bf16 bf16;
typedef __bf16 bf16x4 __attribute__((ext_vector_type(4)));
typedef __bf16 bf16x8 __attribute__((ext_vector_type(8)));
typedef float f32x4 __attribute__((ext_vector_type(4)));

__device__ __forceinline__ f32x4 mfma16(bf16x8 a, bf16x8 b, f32x4 c) {
  return __builtin_amdgcn_mfma_f32_16x16x32_bf16(a, b, c, 0, 0, 0);
}

__device__ __forceinline__ void gload_lds16(const void* g, void* l) {
  __builtin_amdgcn_global_load_lds((__attribute__((address_space(1))) void*)(g),
                                   (__attribute__((address_space(3))) void*)(l),
                                   16, 0, 0);
}

// ---------------- prep: weight cvt + bias concat + LN1 (1 launch) -----------
__global__ __launch_bounds__(256)
void prep(const float* __restrict__ Wq, const float* __restrict__ Wk,
          const float* __restrict__ Wv, const float* __restrict__ Wo,
          const float* __restrict__ W1, const float* __restrict__ W2,
          const float* __restrict__ bq, const float* __restrict__ bk,
          const float* __restrict__ bv, bf16* __restrict__ wqkv,
          bf16* __restrict__ wob, bf16* __restrict__ w1b,
          bf16* __restrict__ w2b, float* __restrict__ bqkv,
          const float* __restrict__ src, const float* __restrict__ g,
          const float* __restrict__ bta, bf16* __restrict__ y) {
  __shared__ float red[8];
  if (blockIdx.x < 12291) {
    const int i = blockIdx.x * 256 + threadIdx.x;
    if (i < 3145728) {
      float4 v;
      bf16* dst;
      size_t di;
      if (i < 262144) { v = ((const float4*)Wq)[i]; dst = wqkv; di = i; }
      else if (i < 524288) { v = ((const float4*)Wk)[i - 262144]; dst = wqkv; di = i; }
      else if (i < 786432) { v = ((const float4*)Wv)[i - 524288]; dst = wqkv; di = i; }
      else if (i < 1048576) { v = ((const float4*)Wo)[i - 786432]; dst = wob; di = i - 786432; }
      else if (i < 2097152) { v = ((const float4*)W1)[i - 1048576]; dst = w1b; di = i - 1048576; }
      else { v = ((const float4*)W2)[i - 2097152]; dst = w2b; di = i - 2097152; }
      bf16x4 o;
      o[0] = (bf16)v.x; o[1] = (bf16)v.y; o[2] = (bf16)v.z; o[3] = (bf16)v.w;
      reinterpret_cast<bf16x4*>(dst)[di] = o;
    } else {
      const int j = i - 3145728;  // 0..767
      const float* s = (j < 256) ? bq : ((j < 512) ? bk : bv);
      reinterpret_cast<float4*>(bqkv)[j] = reinterpret_cast<const float4*>(s)[j & 255];
    }
  } else {
    const int row = blockIdx.x - 12291, t = threadIdx.x;
    const float4 v = reinterpret_cast<const float4*>(src)[(size_t)row * 256 + t];
    float s1 = v.x + v.y + v.z + v.w;
    float s2 = v.x * v.x + v.y * v.y + v.z * v.z + v.w * v.w;
#pragma unroll
    for (int m = 1; m < 64; m <<= 1) {
      s1 += __shfl_xor(s1, m);
      s2 += __shfl_xor(s2, m);
    }
    if ((t & 63) == 0) { red[(t >> 6) * 2] = s1; red[(t >> 6) * 2 + 1] = s2; }
    __syncthreads();
    s1 = red[0] + red[2] + red[4] + red[6];
    s2 = red[1] + red[3] + red[5] + red[7];
    const float mu = s1 * (1.f / 1024.f);
    const float rs = rsqrtf(s2 * (1.f / 1024.f) - mu * mu + 1e-5f);
    const float4 gv = reinterpret_cast<const float4*>(g)[t];
    const float4 bv = reinterpret_cast<const float4*>(bta)[t];
    bf16x4 o;
    o[0] = (bf16)((v.x - mu) * rs * gv.x + bv.x);
    o[1] = (bf16)((v.y - mu) * rs * gv.y + bv.y);
    o[2] = (bf16)((v.z - mu) * rs * gv.z + bv.z);
    o[3] = (bf16)((v.w - mu) * rs * gv.w + bv.w);
    reinterpret_cast<bf16x4*>(y)[(size_t)row * 256 + t] = o;
  }
}

// ---------------- LayerNorm (bf16 input) -> bf16 ----------------------------
__global__ __launch_bounds__(256)
void ln_bf(const bf16* __restrict__ xx, const float* __restrict__ g,
           const float* __restrict__ bta, bf16* __restrict__ y) {
  const int row = blockIdx.x, t = threadIdx.x;
  bf16x4 bv4 = reinterpret_cast<const bf16x4*>(xx)[(size_t)row * 256 + t];
  float4 v;
  v.x = (float)bv4[0]; v.y = (float)bv4[1]; v.z = (float)bv4[2]; v.w = (float)bv4[3];
  float s1 = v.x + v.y + v.z + v.w;
  float s2 = v.x * v.x + v.y * v.y + v.z * v.z + v.w * v.w;
#pragma unroll
  for (int m = 1; m < 64; m <<= 1) {
    s1 += __shfl_xor(s1, m);
    s2 += __shfl_xor(s2, m);
  }
  __shared__ float red[8];
  if ((t & 63) == 0) { red[(t >> 6) * 2] = s1; red[(t >> 6) * 2 + 1] = s2; }
  __syncthreads();
  s1 = red[0] + red[2] + red[4] + red[6];
  s2 = red[1] + red[3] + red[5] + red[7];
  const float mu = s1 * (1.f / 1024.f);
  const float rs = rsqrtf(s2 * (1.f / 1024.f) - mu * mu + 1e-5f);
  const float4 gv = reinterpret_cast<const float4*>(g)[t];
  const float4 bv = reinterpret_cast<const float4*>(bta)[t];
  bf16x4 o;
  o[0] = (bf16)((v.x - mu) * rs * gv.x + bv.x);
  o[1] = (bf16)((v.y - mu) * rs * gv.y + bv.y);
  o[2] = (bf16)((v.z - mu) * rs * gv.z + bv.z);
  o[3] = (bf16)((v.w - mu) * rs * gv.w + bv.w);
  reinterpret_cast<bf16x4*>(y)[(size_t)row * 256 + t] = o;
}

// ---------------- GEMM v3: 128x256 tile, 8 waves, depth-2 -------------------
// VTW: for col>=2048 (QKV V-part) write ONLY to VTo transposed ([b,h,d,s]).
template <bool RELU, bool QSC, bool VTW>
__global__ __launch_bounds__(512)
void gemm_bt3(const bf16* __restrict__ A, const bf16* __restrict__ Bw,
              const float* __restrict__ bias, bf16* __restrict__ Cout,
              bf16* __restrict__ VTo, int M, int N, int K) {
  __shared__ bf16 As[3][128 * 32];  // 8KB each, 64B rows, swizzled
  __shared__ bf16 Bs[3][256 * 32];  // 16KB each
  const int t = threadIdx.x, wave = t >> 6, lane = t & 63;
  const int l15 = lane & 15, lhi = lane >> 4;
  const int nwg = gridDim.x * gridDim.y;
  const int orig = blockIdx.y * gridDim.x + blockIdx.x;
  const int wgid = (orig & 7) * (nwg >> 3) + (orig >> 3);
  const int bx = wgid % gridDim.x, by = wgid / gridDim.x;
  const int m0 = by * 128, n0 = bx * 256;
  const int wm = (wave >> 2) * 64, wn = (wave & 3) * 64;
  const f32x4 z4 = {0.f, 0.f, 0.f, 0.f};
  f32x4 acc[4][4];
#pragma unroll
  for (int m = 0; m < 4; ++m)
#pragma unroll
    for (int n = 0; n < 4; ++n) acc[m][n] = z4;

  const int da = t * 16;
  const int ra = da >> 6, ca = (da & 63) ^ (((ra >> 2) & 3) << 4);
  const bf16* agp = A + (size_t)(m0 + ra) * K + (ca >> 1);
  int db_[2];
  const bf16* bgp[2];
#pragma unroll
  for (int j = 0; j < 2; ++j) {
    db_[j] = j * 8192 + t * 16;
    const int rb = db_[j] >> 6;
    const int cb = (db_[j] & 63) ^ (((rb >> 2) & 3) << 4);
    bgp[j] = Bw + (size_t)(n0 + rb) * K + (cb >> 1);
  }

#define G3_STAGE(k0, bb)                                                      \
  do {                                                                        \
    gload_lds16(agp + (k0), (char*)As[bb] + da);                              \
    gload_lds16(bgp[0] + (k0), (char*)Bs[bb] + db_[0]);                       \
    gload_lds16(bgp[1] + (k0), (char*)Bs[bb] + db_[1]);                       \
  } while (0)

  const int nt = K >> 5;
  G3_STAGE(0, 0);
  G3_STAGE(32, 1);
  asm volatile("s_waitcnt vmcnt(3)" ::: "memory");  // tile 0 landed
  __builtin_amdgcn_s_barrier();

  for (int kt = 0; kt < nt; ++kt) {
    if (kt + 2 < nt) G3_STAGE((kt + 2) * 32, (kt + 2) % 3);
    const char* Ac = (const char*)As[kt % 3];
    const char* Bc = (const char*)Bs[kt % 3];
    bf16x8 af[4], bfr[4];
#pragma unroll
    for (int m = 0; m < 4; ++m) {
      const int row = wm + m * 16 + l15;
      af[m] = *reinterpret_cast<const bf16x8*>(
          Ac + row * 64 + ((lhi * 16) ^ (((row >> 2) & 3) << 4)));
    }
#pragma unroll
    for (int n = 0; n < 4; ++n) {
      const int row = wn + n * 16 + l15;
      bfr[n] = *reinterpret_cast<const bf16x8*>(
          Bc + row * 64 + ((lhi * 16) ^ (((row >> 2) & 3) << 4)));
    }
    __builtin_amdgcn_s_setprio(1);
#pragma unroll
    for (int m = 0; m < 4; ++m)
#pragma unroll
      for (int n = 0; n < 4; ++n) acc[m][n] = mfma16(af[m], bfr[n], acc[m][n]);
    __builtin_amdgcn_s_setprio(0);
    if (kt + 1 < nt) {
      if (kt + 2 < nt)
        asm volatile("s_waitcnt vmcnt(3)" ::: "memory");  // t+1 landed
      else
        asm volatile("s_waitcnt vmcnt(0)" ::: "memory");
      __builtin_amdgcn_s_barrier();
    }
  }
#undef G3_STAGE

  const float sc = (QSC && n0 < 1024) ? 0.18033688011112042f : 1.0f;  // 0.125*log2e
#pragma unroll
  for (int m = 0; m < 4; ++m) {
    const int row_base = m0 + wm + m * 16 + lhi * 4;
#pragma unroll
    for (int n = 0; n < 4; ++n) {
      const int col = n0 + wn + n * 16 + l15;
      const float bv = bias[col];
      if (VTW && col >= 2048) {
        const int hd = col - 2048, hh = hd >> 6, d = hd & 63;
        const int bb = row_base >> 11, s = row_base & 2047;
        bf16x4 vv;
#pragma unroll
        for (int r = 0; r < 4; ++r) vv[r] = (bf16)(acc[m][n][r] + bv);
        *reinterpret_cast<bf16x4*>(
            VTo + ((size_t)((bb * 16 + hh) * 64 + d) * 2048 + s)) = vv;
      } else {
#pragma unroll
        for (int r = 0; r < 4; ++r) {
          float v = (acc[m][n][r] + bv) * sc;
          if (RELU) v = v > 0.f ? v : 0.f;
          Cout[(size_t)(row_base + r) * N + col] = (bf16)v;
        }
      }
    }
  }
}

// ---------------- GEMM small-N: 64x128 tile, 4 waves, depth-3 ---------------
template <bool OUT_BF16, bool RES, bool RESBF>
__global__ __launch_bounds__(256)
void gemm_bt(const bf16* __restrict__ A, const bf16* __restrict__ Bw,
             const float* __restrict__ bias, const void* __restrict__ res,
             void* __restrict__ Cout, int M, int N, int K) {
  __shared__ bf16 As[4][64 * 32];    // 4KB each
  __shared__ bf16 Bs[4][128 * 32];   // 8KB each
  const int t = threadIdx.x, wave = t >> 6, lane = t & 63;
  const int l15 = lane & 15, lhi = lane >> 4;
  const int nwg = gridDim.x * gridDim.y;
  const int orig = blockIdx.y * gridDim.x + blockIdx.x;
  const int wgid = (orig & 7) * (nwg >> 3) + (orig >> 3);
  const int bx = wgid % gridDim.x, by = wgid / gridDim.x;
  const int m0 = by * 64, n0 = bx * 128;
  const int wm = (wave >> 1) * 32, wn = (wave & 1) * 64;
  const f32x4 z4 = {0.f, 0.f, 0.f, 0.f};
  f32x4 acc[2][4];
#pragma unroll
  for (int m = 0; m < 2; ++m)
#pragma unroll
    for (int n = 0; n < 4; ++n) acc[m][n] = z4;

  int soff[2], srow[2], scol[2];
#pragma unroll
  for (int i = 0; i < 2; ++i) {
    soff[i] = (i * 4 + wave) * 1024 + lane * 16;
    srow[i] = soff[i] >> 6;
    scol[i] = ((soff[i] & 63) ^ (((srow[i] >> 2) & 3) << 4)) >> 1;
  }

#define GEMM_STAGE(k0, bb)                                                    \
  do {                                                                        \
    gload_lds16(A + (size_t)(m0 + srow[0]) * K + (k0) + scol[0],              \
                (char*)As[bb] + soff[0]);                                     \
    gload_lds16(Bw + (size_t)(n0 + srow[0]) * K + (k0) + scol[0],             \
                (char*)Bs[bb] + soff[0]);                                     \
    gload_lds16(Bw + (size_t)(n0 + srow[1]) * K + (k0) + scol[1],             \
                (char*)Bs[bb] + soff[1]);                                     \
  } while (0)

  const int nt = K >> 5;
  GEMM_STAGE(0, 0);
  GEMM_STAGE(32, 1);
  GEMM_STAGE(64, 2);
  asm volatile("s_waitcnt vmcnt(6)" ::: "memory");  // tile 0 landed
  __builtin_amdgcn_s_barrier();

  for (int kt = 0; kt < nt; ++kt) {
    if (kt + 3 < nt) GEMM_STAGE((kt + 3) * 32, (kt + 3) & 3);
    const char* Ac = (const char*)As[kt & 3];
    const char* Bc = (const char*)Bs[kt & 3];
    bf16x8 af[2], bfr[4];
#pragma unroll
    for (int m = 0; m < 2; ++m) {
      const int row = wm + m * 16 + l15;
      af[m] = *reinterpret_cast<const bf16x8*>(
          Ac + row * 64 + ((lhi * 16) ^ (((row >> 2) & 3) << 4)));
    }
#pragma unroll
    for (int n = 0; n < 4; ++n) {
      const int row = wn + n * 16 + l15;
      bfr[n] = *reinterpret_cast<const bf16x8*>(
          Bc + row * 64 + ((lhi * 16) ^ (((row >> 2) & 3) << 4)));
    }
    __builtin_amdgcn_s_setprio(1);
#pragma unroll
    for (int m = 0; m < 2; ++m)
#pragma unroll
      for (int n = 0; n < 4; ++n) acc[m][n] = mfma16(af[m], bfr[n], acc[m][n]);
    __builtin_amdgcn_s_setprio(0);
    if (kt + 1 < nt) {
      if (kt + 3 < nt)
        asm volatile("s_waitcnt vmcnt(6)" ::: "memory");  // t+1 landed
      else if (kt + 2 < nt)
        asm volatile("s_waitcnt vmcnt(3)" ::: "memory");  // drain tail
      else
        asm volatile("s_waitcnt vmcnt(0)" ::: "memory");
      __builtin_amdgcn_s_barrier();
    }
  }
#undef GEMM_STAGE

#pragma unroll
  for (int m = 0; m < 2; ++m) {
    const int row_base = m0 + wm + m * 16 + lhi * 4;
#pragma unroll
    for (int n = 0; n < 4; ++n) {
      const int col = n0 + wn + n * 16 + l15;
      const float bv = bias[col];
#pragma unroll
      for (int r = 0; r < 4; ++r) {
        const int row = row_base + r;
        float v = acc[m][n][r] + bv;
        if (RES) {
          const size_t idx = (size_t)row * N + col;
          v += RESBF ? (float)((const bf16*)res)[idx] : ((const float*)res)[idx];
        }
        if (OUT_BF16)
          ((bf16*)Cout)[(size_t)row * N + col] = (bf16)v;
        else
          ((float*)Cout)[(size_t)row * N + col] = v;
      }
    }
  }
}

// ---------------- Fused attention: QBLK=128, 8 waves ------------------------
// Pass A: KB=256 (2x32KB ping over [0,64K)), 8 tiles, 1 barrier/tile.
// Pass B: KB=64 ping (Kb [0,16K), Vb [16K,32K)), P at [32K,48K), 1 barrier/tile.
// launch_bounds(512,4) pins VGPR<=128 -> guaranteed 2 blocks/CU at 66KB LDS.
__global__ __launch_bounds__(512, 4)
void attn_fused2(const bf16* __restrict__ Qp, const bf16* __restrict__ Kp,
                 const bf16* __restrict__ VTp, const int* __restrict__ mask,
                 float* __restrict__ probs, bf16* __restrict__ Ob) {
  constexpr int S = 2048, LD = 3072;
  __shared__ char lds[67584];  // 64K data + 2K msk
  const int t = threadIdx.x, wave = t >> 6, lane = t & 63;
  const int l15 = lane & 15, lhi = lane >> 4;
  const int flat = blockIdx.x + 16 * (blockIdx.y + 16 * blockIdx.z);
  const int wg = (flat & 7) * 64 + (flat >> 3);
  const int q0 = (wg & 15) * 128, h = (wg >> 4) & 15, b = wg >> 8;
  const int* mrow = mask + b * S;
  const f32x4 z4 = {0.f, 0.f, 0.f, 0.f};
  float* mskA = (float*)(lds + 65536);  // [2][256] (pass B: [2][64])

  // pass A staging map (KB=256): 4 chunks of 16B per thread (32KB tile)
  const bf16* kgpA[4];
  int soffA[4];
#pragma unroll
  for (int i = 0; i < 4; ++i) {
    const int off = (i * 8 + wave) * 1024 + lane * 16;
    soffA[i] = off;
    const int krow = off >> 7, kbin = off & 127;
    kgpA[i] = Kp + (size_t)(b * S + krow) * LD + h * 64 + ((kbin ^ ((krow & 7) << 4)) >> 1);
  }

  bf16x8 qf[2];
#pragma unroll
  for (int ks = 0; ks < 2; ++ks)
    qf[ks] = *reinterpret_cast<const bf16x8*>(
        Qp + (size_t)(b * S + q0 + wave * 16 + l15) * LD + h * 64 + ks * 32 + lhi * 8);

  // ================= pass A: l = sum over kv of exp2(s), KB=256 =============
  bf16x8 kreg[4];
  float mnext;
#pragma unroll
  for (int i = 0; i < 4; ++i) kreg[i] = *reinterpret_cast<const bf16x8*>(kgpA[i]);
  mnext = (t < 256) ? (mrow[t] ? 0.f : 1.f) : 0.f;
#pragma unroll
  for (int i = 0; i < 4; ++i)
    *reinterpret_cast<bf16x8*>(lds + soffA[i]) = kreg[i];
  if (t < 256) mskA[t] = mnext;
  __syncthreads();

  float lpart = 0.f;
  for (int kt = 0; kt < 8; ++kt) {
    const int kv0 = kt * 256;
    if (kt + 1 < 8) {  // issue-early
#pragma unroll
      for (int i = 0; i < 4; ++i)
        kreg[i] = *reinterpret_cast<const bf16x8*>(kgpA[i] + (size_t)(kv0 + 256) * LD);
      mnext = (t < 256) ? (mrow[kv0 + 256 + t] ? 0.f : 1.f) : 0.f;
    }
    const char* kb = lds + (kt & 1) * 32768;
    const float* mc = mskA + (kt & 1) * 256;
#pragma unroll
    for (int g = 0; g < 4; ++g) {  // four 64-kv groups
      f32x4 sa[4];
#pragma unroll
      for (int n = 0; n < 4; ++n) sa[n] = z4;
      __builtin_amdgcn_s_setprio(1);
#pragma unroll
      for (int ks = 0; ks < 2; ++ks)
#pragma unroll
        for (int n = 0; n < 4; ++n) {
          const int krow = g * 64 + n * 16 + l15;
          bf16x8 kf = *reinterpret_cast<const bf16x8*>(
              kb + krow * 128 + ((ks * 64 + lhi * 16) ^ ((krow & 7) << 4)));
          sa[n] = mfma16(kf, qf[ks], sa[n]);
        }
      __builtin_amdgcn_s_setprio(0);
#pragma unroll
      for (int n = 0; n < 4; ++n)
#pragma unroll
        for (int r = 0; r < 4; ++r)
          lpart += __builtin_exp2f(sa[n][r]) * mc[g * 64 + n * 16 + lhi * 4 + r];
    }
    if (kt + 1 < 8) {  // write-late into the OTHER region
      char* kbn = lds + ((kt + 1) & 1) * 32768;
#pragma unroll
      for (int i = 0; i < 4; ++i)
        *reinterpret_cast<bf16x8*>(kbn + soffA[i]) = kreg[i];
      if (t < 256) mskA[((kt + 1) & 1) * 256 + t] = mnext;
    }
    __syncthreads();
  }
  lpart += __shfl_xor(lpart, 16);
  lpart += __shfl_xor(lpart, 32);
  const float il = 1.f / lpart;

  // ================= pass B: probs + PV, KB=64, 1 barrier/tile ==============
  const int offB = t * 16;
  const int krB = offB >> 7, binB = offB & 127;
  const int swB = (binB ^ ((krB & 7) << 4)) >> 1;
  const bf16* kgpB = Kp + (size_t)(b * S + krB) * LD + h * 64 + swB;
  const bf16* vgpB = VTp + (size_t)((b * 16 + h) * 64 + krB) * S + swB;
  char* Pb = lds + 32768;

  f32x4 oa[4];
#pragma unroll
  for (int n = 0; n < 4; ++n) oa[n] = z4;
  float* pbase = probs + ((size_t)(b * 16 + h) * S + q0 + wave * 16 + l15) * S;
  const int prw = wave * 16 + l15;
  const int swzp = (prw & 7) << 4;

  bf16x8 krg = *reinterpret_cast<const bf16x8*>(kgpB);
  bf16x8 vrg = *reinterpret_cast<const bf16x8*>(vgpB);
  float mnb = (t < 64) ? (mrow[t] ? 0.f : 1.f) : 0.f;
  // pass A's final barrier passed: safe to overwrite lds[0..64K)
  *reinterpret_cast<bf16x8*>(lds + offB) = krg;          // Kb[0]
  *reinterpret_cast<bf16x8*>(lds + 16384 + offB) = vrg;  // Vb[0]
  if (t < 64) mskA[t] = mnb;
  __syncthreads();

  for (int kt = 0; kt < 32; ++kt) {
    const int kv0 = kt * 64;
    if (kt + 1 < 32) {  // issue-early
      krg = *reinterpret_cast<const bf16x8*>(kgpB + (size_t)(kv0 + 64) * LD);
      vrg = *reinterpret_cast<const bf16x8*>(vgpB + kv0 + 64);
      mnb = (t < 64) ? (mrow[kv0 + 64 + t] ? 0.f : 1.f) : 0.f;
    }
    const char* kc = lds + (kt & 1) * 8192;
    const char* vc = lds + 16384 + (kt & 1) * 8192;
    const float* mc = mskA + (kt & 1) * 64;

    f32x4 sa[4];
#pragma unroll
    for (int n = 0; n < 4; ++n) sa[n] = z4;
    __builtin_amdgcn_s_setprio(1);
#pragma unroll
    for (int ks = 0; ks < 2; ++ks)
#pragma unroll
      for (int n = 0; n < 4; ++n) {
        const int krow = n * 16 + l15;
        bf16x8 kf = *reinterpret_cast<const bf16x8*>(
            kc + krow * 128 + ((ks * 64 + lhi * 16) ^ ((krow & 7) << 4)));
        sa[n] = mfma16(kf, qf[ks], sa[n]);
      }
    __builtin_amdgcn_s_setprio(0);

#pragma unroll
    for (int n = 0; n < 4; ++n) {
      f32x4 praw, pn;
#pragma unroll
      for (int r = 0; r < 4; ++r) {
        praw[r] = __builtin_exp2f(sa[n][r]) * mc[n * 16 + lhi * 4 + r];
        pn[r] = praw[r] * il;
      }
      __builtin_nontemporal_store(pn, reinterpret_cast<f32x4*>(pbase + kv0 + n * 16 + lhi * 4));
      bf16x4 pb;
      pb[0] = (bf16)praw[0]; pb[1] = (bf16)praw[1];
      pb[2] = (bf16)praw[2]; pb[3] = (bf16)praw[3];
      *reinterpret_cast<bf16x4*>(Pb + prw * 128 + ((n * 32 + lhi * 8) ^ swzp)) = pb;
    }
    __builtin_amdgcn_s_setprio(1);
#pragma unroll
    for (int ks = 0; ks < 2; ++ks) {
      bf16x8 pf = *reinterpret_cast<const bf16x8*>(
          Pb + prw * 128 + ((ks * 64 + lhi * 16) ^ swzp));
#pragma unroll
      for (int nn = 0; nn < 4; ++nn) {
        const int vr = nn * 16 + l15;
        bf16x8 vf = *reinterpret_cast<const bf16x8*>(
            vc + vr * 128 + ((ks * 64 + lhi * 16) ^ ((vr & 7) << 4)));
        oa[nn] = mfma16(pf, vf, oa[nn]);
      }
    }
    __builtin_amdgcn_s_setprio(0);
    if (kt + 1 < 32) {  // write-late into the OTHER buffers
      *reinterpret_cast<bf16x8*>(lds + ((kt + 1) & 1) * 8192 + offB) = krg;
      *reinterpret_cast<bf16x8*>(lds + 16384 + ((kt + 1) & 1) * 8192 + offB) = vrg;
      if (t < 64) mskA[((kt + 1) & 1) * 64 + t] = mnb;
    }
    __syncthreads();
  }

  float il4[4];
#pragma unroll
  for (int r = 0; r < 4; ++r) il4[r] = __shfl(il, lhi * 4 + r);
#pragma unroll
  for (int nn = 0; nn < 4; ++nn)
#pragma unroll
    for (int r = 0; r < 4; ++r)
      Ob[(size_t)(b * S + q0 + wave * 16 + lhi * 4 + r) * 1024 + h * 64 + nn * 16 + l15] =
          (bf16)(oa[nn][r] * il4[r]);
}

// ---------------- launch ----------------
extern "C" void kernel_launch(void* const* d_in, const int* in_sizes, int n_in,
                              void* d_out, int out_size, void* d_ws, size_t ws_size,
                              hipStream_t stream) {
  const float* src = (const float*)d_in[0];
  const int* mask = (const int*)d_in[1];
  const float* Wq = (const float*)d_in[2];
  const float* bq = (const float*)d_in[3];
  const float* Wk = (const float*)d_in[4];
  const float* bk = (const float*)d_in[5];
  const float* Wv = (const float*)d_in[6];
  const float* bv = (const float*)d_in[7];
  const float* Wo = (const float*)d_in[8];
  const float* bo = (const float*)d_in[9];
  const float* W1 = (const float*)d_in[10];
  const float* b1 = (const float*)d_in[11];
  const float* W2 = (const float*)d_in[12];
  const float* b2 = (const float*)d_in[13];
  const float* ln1g = (const float*)d_in[14];
  const float* ln1b = (const float*)d_in[15];
  const float* ln2g = (const float*)d_in[16];
  const float* ln2b = (const float*)d_in[17];

  float* out0 = (float*)d_out;                       // [2,2048,1024]
  float* probs = (float*)d_out + (size_t)4194304;    // [2,16,2048,2048]

  char* w = (char*)d_ws;
  const size_t MB = 1u << 20;
  bf16* wqkv = (bf16*)(w);              // [3072,1024] rows: Wq|Wk|Wv (6MB)
  bf16* wob = (bf16*)(w + 6 * MB);      // [1024,1024]
  bf16* w1b = (bf16*)(w + 8 * MB);      // [4096,1024]
  bf16* w2b = (bf16*)(w + 16 * MB);     // [1024,4096]
  bf16* xn = (bf16*)(w + 24 * MB);      // [4096,1024]
  bf16* QKV = (bf16*)(w + 32 * MB);     // [4096,3072] (24MB; V cols unused)
  bf16* Ob = (bf16*)(w + 56 * MB);      // [4096,1024]
  bf16* hb = (bf16*)(w + 32 * MB);      // [4096,4096] reuse (QKV dead by then)
  bf16* VT = (bf16*)(w + 64 * MB);      // [2,16,64,2048] (8MB); dead after attn
  bf16* s2 = (bf16*)(w + 72 * MB);      // [4096,1024] bf16 (8MB)
  float* bqkv = (float*)(w + 80 * MB);  // [3072]

  // prep: weight conversion + bias concat + LN1 (1 launch)
  prep<<<16387, 256, 0, stream>>>(Wq, Wk, Wv, Wo, W1, W2, bq, bk, bv,
                                  wqkv, wob, w1b, w2b, bqkv,
                                  src, ln1g, ln1b, xn);
  // fused QKV projection (Q pre-scaled by 0.125*log2e; V written transposed to VT)
  gemm_bt3<false, true, true><<<dim3(12, 32), 512, 0, stream>>>(
      xn, wqkv, bqkv, QKV, VT, 4096, 3072, 1024);
  // fused attention (QBLK=128, 8 waves; pass A KB=256, pass B KB=64)
  attn_fused2<<<dim3(16, 16, 2), 512, 0, stream>>>(
      QKV, QKV + 1024, VT, mask, probs, Ob);
  // Wo + residual(src fp32) -> s2 (bf16): 64x128 tile, 512 blocks, depth-3
  gemm_bt<true, true, false><<<dim3(8, 64), 256, 0, stream>>>(
      Ob, wob, bo, src, s2, 4096, 1024, 1024);
  // LN2 (bf16 input)
  ln_bf<<<4096, 256, 0, stream>>>(s2, ln2g, ln2b, xn);
  // FFN1 + ReLU: v3
  gemm_bt3<true, false, false><<<dim3(16, 32), 512, 0, stream>>>(
      xn, w1b, b1, hb, nullptr, 4096, 4096, 1024);
  // FFN2 + residual(s2 bf16) -> out0 (fp32): 64x128 tile, 512 blocks, depth-3
  gemm_bt<false, true, true><<<dim3(8, 64), 256, 0, stream>>>(
      hb, w2b, b2, s2, out0, 4096, 1024, 4096);

  (void)in_sizes; (void)n_in; (void)out_size; (void)ws_size;
}

// Round 19
// 394.428 us; speedup vs baseline: 1.2479x; 1.2479x over previous
//
#include <hip/hip_runtime.h>
#include <math.h>

typedef __bf16 bf16;
typedef __bf16 bf16x4 __attribute__((ext_vector_type(4)));
typedef __bf16 bf16x8 __attribute__((ext_vector_type(8)));
typedef float f32x4 __attribute__((ext_vector_type(4)));

__device__ __forceinline__ f32x4 mfma16(bf16x8 a, bf16x8 b, f32x4 c) {
  return __builtin_amdgcn_mfma_f32_16x16x32_bf16(a, b, c, 0, 0, 0);
}

__device__ __forceinline__ void gload_lds16(const void* g, void* l) {
  __builtin_amdgcn_global_load_lds((__attribute__((address_space(1))) void*)(g),
                                   (__attribute__((address_space(3))) void*)(l),
                                   16, 0, 0);
}

// ---------------- prep: weight cvt + bias concat + LN1 (1 launch) -----------
__global__ __launch_bounds__(256)
void prep(const float* __restrict__ Wq, const float* __restrict__ Wk,
          const float* __restrict__ Wv, const float* __restrict__ Wo,
          const float* __restrict__ W1, const float* __restrict__ W2,
          const float* __restrict__ bq, const float* __restrict__ bk,
          const float* __restrict__ bv, bf16* __restrict__ wqkv,
          bf16* __restrict__ wob, bf16* __restrict__ w1b,
          bf16* __restrict__ w2b, float* __restrict__ bqkv,
          const float* __restrict__ src, const float* __restrict__ g,
          const float* __restrict__ bta, bf16* __restrict__ y) {
  __shared__ float red[8];
  if (blockIdx.x < 12291) {
    const int i = blockIdx.x * 256 + threadIdx.x;
    if (i < 3145728) {
      float4 v;
      bf16* dst;
      size_t di;
      if (i < 262144) { v = ((const float4*)Wq)[i]; dst = wqkv; di = i; }
      else if (i < 524288) { v = ((const float4*)Wk)[i - 262144]; dst = wqkv; di = i; }
      else if (i < 786432) { v = ((const float4*)Wv)[i - 524288]; dst = wqkv; di = i; }
      else if (i < 1048576) { v = ((const float4*)Wo)[i - 786432]; dst = wob; di = i - 786432; }
      else if (i < 2097152) { v = ((const float4*)W1)[i - 1048576]; dst = w1b; di = i - 1048576; }
      else { v = ((const float4*)W2)[i - 2097152]; dst = w2b; di = i - 2097152; }
      bf16x4 o;
      o[0] = (bf16)v.x; o[1] = (bf16)v.y; o[2] = (bf16)v.z; o[3] = (bf16)v.w;
      reinterpret_cast<bf16x4*>(dst)[di] = o;
    } else {
      const int j = i - 3145728;  // 0..767
      const float* s = (j < 256) ? bq : ((j < 512) ? bk : bv);
      reinterpret_cast<float4*>(bqkv)[j] = reinterpret_cast<const float4*>(s)[j & 255];
    }
  } else {
    const int row = blockIdx.x - 12291, t = threadIdx.x;
    const float4 v = reinterpret_cast<const float4*>(src)[(size_t)row * 256 + t];
    float s1 = v.x + v.y + v.z + v.w;
    float s2 = v.x * v.x + v.y * v.y + v.z * v.z + v.w * v.w;
#pragma unroll
    for (int m = 1; m < 64; m <<= 1) {
      s1 += __shfl_xor(s1, m);
      s2 += __shfl_xor(s2, m);
    }
    if ((t & 63) == 0) { red[(t >> 6) * 2] = s1; red[(t >> 6) * 2 + 1] = s2; }
    __syncthreads();
    s1 = red[0] + red[2] + red[4] + red[6];
    s2 = red[1] + red[3] + red[5] + red[7];
    const float mu = s1 * (1.f / 1024.f);
    const float rs = rsqrtf(s2 * (1.f / 1024.f) - mu * mu + 1e-5f);
    const float4 gv = reinterpret_cast<const float4*>(g)[t];
    const float4 bv = reinterpret_cast<const float4*>(bta)[t];
    bf16x4 o;
    o[0] = (bf16)((v.x - mu) * rs * gv.x + bv.x);
    o[1] = (bf16)((v.y - mu) * rs * gv.y + bv.y);
    o[2] = (bf16)((v.z - mu) * rs * gv.z + bv.z);
    o[3] = (bf16)((v.w - mu) * rs * gv.w + bv.w);
    reinterpret_cast<bf16x4*>(y)[(size_t)row * 256 + t] = o;
  }
}

// ---------------- LayerNorm (bf16 input) -> bf16 ----------------------------
__global__ __launch_bounds__(256)
void ln_bf(const bf16* __restrict__ xx, const float* __restrict__ g,
           const float* __restrict__ bta, bf16* __restrict__ y) {
  const int row = blockIdx.x, t = threadIdx.x;
  bf16x4 bv4 = reinterpret_cast<const bf16x4*>(xx)[(size_t)row * 256 + t];
  float4 v;
  v.x = (float)bv4[0]; v.y = (float)bv4[1]; v.z = (float)bv4[2]; v.w = (float)bv4[3];
  float s1 = v.x + v.y + v.z + v.w;
  float s2 = v.x * v.x + v.y * v.y + v.z * v.z + v.w * v.w;
#pragma unroll
  for (int m = 1; m < 64; m <<= 1) {
    s1 += __shfl_xor(s1, m);
    s2 += __shfl_xor(s2, m);
  }
  __shared__ float red[8];
  if ((t & 63) == 0) { red[(t >> 6) * 2] = s1; red[(t >> 6) * 2 + 1] = s2; }
  __syncthreads();
  s1 = red[0] + red[2] + red[4] + red[6];
  s2 = red[1] + red[3] + red[5] + red[7];
  const float mu = s1 * (1.f / 1024.f);
  const float rs = rsqrtf(s2 * (1.f / 1024.f) - mu * mu + 1e-5f);
  const float4 gv = reinterpret_cast<const float4*>(g)[t];
  const float4 bv = reinterpret_cast<const float4*>(bta)[t];
  bf16x4 o;
  o[0] = (bf16)((v.x - mu) * rs * gv.x + bv.x);
  o[1] = (bf16)((v.y - mu) * rs * gv.y + bv.y);
  o[2] = (bf16)((v.z - mu) * rs * gv.z + bv.z);
  o[3] = (bf16)((v.w - mu) * rs * gv.w + bv.w);
  reinterpret_cast<bf16x4*>(y)[(size_t)row * 256 + t] = o;
}

// ---------------- GEMM v3: 128x256 tile, 8 waves, depth-2 -------------------
// VTW: for col>=2048 (QKV V-part) write ONLY to VTo transposed ([b,h,d,s]).
template <bool RELU, bool QSC, bool VTW>
__global__ __launch_bounds__(512)
void gemm_bt3(const bf16* __restrict__ A, const bf16* __restrict__ Bw,
              const float* __restrict__ bias, bf16* __restrict__ Cout,
              bf16* __restrict__ VTo, int M, int N, int K) {
  __shared__ bf16 As[3][128 * 32];  // 8KB each, 64B rows, swizzled
  __shared__ bf16 Bs[3][256 * 32];  // 16KB each
  const int t = threadIdx.x, wave = t >> 6, lane = t & 63;
  const int l15 = lane & 15, lhi = lane >> 4;
  const int nwg = gridDim.x * gridDim.y;
  const int orig = blockIdx.y * gridDim.x + blockIdx.x;
  const int wgid = (orig & 7) * (nwg >> 3) + (orig >> 3);
  const int bx = wgid % gridDim.x, by = wgid / gridDim.x;
  const int m0 = by * 128, n0 = bx * 256;
  const int wm = (wave >> 2) * 64, wn = (wave & 3) * 64;
  const f32x4 z4 = {0.f, 0.f, 0.f, 0.f};
  f32x4 acc[4][4];
#pragma unroll
  for (int m = 0; m < 4; ++m)
#pragma unroll
    for (int n = 0; n < 4; ++n) acc[m][n] = z4;

  const int da = t * 16;
  const int ra = da >> 6, ca = (da & 63) ^ (((ra >> 2) & 3) << 4);
  const bf16* agp = A + (size_t)(m0 + ra) * K + (ca >> 1);
  int db_[2];
  const bf16* bgp[2];
#pragma unroll
  for (int j = 0; j < 2; ++j) {
    db_[j] = j * 8192 + t * 16;
    const int rb = db_[j] >> 6;
    const int cb = (db_[j] & 63) ^ (((rb >> 2) & 3) << 4);
    bgp[j] = Bw + (size_t)(n0 + rb) * K + (cb >> 1);
  }

#define G3_STAGE(k0, bb)                                                      \
  do {                                                                        \
    gload_lds16(agp + (k0), (char*)As[bb] + da);                              \
    gload_lds16(bgp[0] + (k0), (char*)Bs[bb] + db_[0]);                       \
    gload_lds16(bgp[1] + (k0), (char*)Bs[bb] + db_[1]);                       \
  } while (0)

  const int nt = K >> 5;
  G3_STAGE(0, 0);
  G3_STAGE(32, 1);
  asm volatile("s_waitcnt vmcnt(3)" ::: "memory");  // tile 0 landed
  __builtin_amdgcn_s_barrier();

  for (int kt = 0; kt < nt; ++kt) {
    if (kt + 2 < nt) G3_STAGE((kt + 2) * 32, (kt + 2) % 3);
    const char* Ac = (const char*)As[kt % 3];
    const char* Bc = (const char*)Bs[kt % 3];
    bf16x8 af[4], bfr[4];
#pragma unroll
    for (int m = 0; m < 4; ++m) {
      const int row = wm + m * 16 + l15;
      af[m] = *reinterpret_cast<const bf16x8*>(
          Ac + row * 64 + ((lhi * 16) ^ (((row >> 2) & 3) << 4)));
    }
#pragma unroll
    for (int n = 0; n < 4; ++n) {
      const int row = wn + n * 16 + l15;
      bfr[n] = *reinterpret_cast<const bf16x8*>(
          Bc + row * 64 + ((lhi * 16) ^ (((row >> 2) & 3) << 4)));
    }
    __builtin_amdgcn_s_setprio(1);
#pragma unroll
    for (int m = 0; m < 4; ++m)
#pragma unroll
      for (int n = 0; n < 4; ++n) acc[m][n] = mfma16(af[m], bfr[n], acc[m][n]);
    __builtin_amdgcn_s_setprio(0);
    if (kt + 1 < nt) {
      if (kt + 2 < nt)
        asm volatile("s_waitcnt vmcnt(3)" ::: "memory");  // t+1 landed
      else
        asm volatile("s_waitcnt vmcnt(0)" ::: "memory");
      __builtin_amdgcn_s_barrier();
    }
  }
#undef G3_STAGE

  const float sc = (QSC && n0 < 1024) ? 0.18033688011112042f : 1.0f;  // 0.125*log2e
#pragma unroll
  for (int m = 0; m < 4; ++m) {
    const int row_base = m0 + wm + m * 16 + lhi * 4;
#pragma unroll
    for (int n = 0; n < 4; ++n) {
      const int col = n0 + wn + n * 16 + l15;
      const float bv = bias[col];
      if (VTW && col >= 2048) {
        const int hd = col - 2048, hh = hd >> 6, d = hd & 63;
        const int bb = row_base >> 11, s = row_base & 2047;
        bf16x4 vv;
#pragma unroll
        for (int r = 0; r < 4; ++r) vv[r] = (bf16)(acc[m][n][r] + bv);
        *reinterpret_cast<bf16x4*>(
            VTo + ((size_t)((bb * 16 + hh) * 64 + d) * 2048 + s)) = vv;
      } else {
#pragma unroll
        for (int r = 0; r < 4; ++r) {
          float v = (acc[m][n][r] + bv) * sc;
          if (RELU) v = v > 0.f ? v : 0.f;
          Cout[(size_t)(row_base + r) * N + col] = (bf16)v;
        }
      }
    }
  }
}

// ---------------- GEMM small-N: 64x128 tile, 4 waves, depth-3 ---------------
template <bool OUT_BF16, bool RES, bool RESBF>
__global__ __launch_bounds__(256)
void gemm_bt(const bf16* __restrict__ A, const bf16* __restrict__ Bw,
             const float* __restrict__ bias, const void* __restrict__ res,
             void* __restrict__ Cout, int M, int N, int K) {
  __shared__ bf16 As[4][64 * 32];    // 4KB each
  __shared__ bf16 Bs[4][128 * 32];   // 8KB each
  const int t = threadIdx.x, wave = t >> 6, lane = t & 63;
  const int l15 = lane & 15, lhi = lane >> 4;
  const int nwg = gridDim.x * gridDim.y;
  const int orig = blockIdx.y * gridDim.x + blockIdx.x;
  const int wgid = (orig & 7) * (nwg >> 3) + (orig >> 3);
  const int bx = wgid % gridDim.x, by = wgid / gridDim.x;
  const int m0 = by * 64, n0 = bx * 128;
  const int wm = (wave >> 1) * 32, wn = (wave & 1) * 64;
  const f32x4 z4 = {0.f, 0.f, 0.f, 0.f};
  f32x4 acc[2][4];
#pragma unroll
  for (int m = 0; m < 2; ++m)
#pragma unroll
    for (int n = 0; n < 4; ++n) acc[m][n] = z4;

  int soff[2], srow[2], scol[2];
#pragma unroll
  for (int i = 0; i < 2; ++i) {
    soff[i] = (i * 4 + wave) * 1024 + lane * 16;
    srow[i] = soff[i] >> 6;
    scol[i] = ((soff[i] & 63) ^ (((srow[i] >> 2) & 3) << 4)) >> 1;
  }

#define GEMM_STAGE(k0, bb)                                                    \
  do {                                                                        \
    gload_lds16(A + (size_t)(m0 + srow[0]) * K + (k0) + scol[0],              \
                (char*)As[bb] + soff[0]);                                     \
    gload_lds16(Bw + (size_t)(n0 + srow[0]) * K + (k0) + scol[0],             \
                (char*)Bs[bb] + soff[0]);                                     \
    gload_lds16(Bw + (size_t)(n0 + srow[1]) * K + (k0) + scol[1],             \
                (char*)Bs[bb] + soff[1]);                                     \
  } while (0)

  const int nt = K >> 5;
  GEMM_STAGE(0, 0);
  GEMM_STAGE(32, 1);
  GEMM_STAGE(64, 2);
  asm volatile("s_waitcnt vmcnt(6)" ::: "memory");  // tile 0 landed
  __builtin_amdgcn_s_barrier();

  for (int kt = 0; kt < nt; ++kt) {
    if (kt + 3 < nt) GEMM_STAGE((kt + 3) * 32, (kt + 3) & 3);
    const char* Ac = (const char*)As[kt & 3];
    const char* Bc = (const char*)Bs[kt & 3];
    bf16x8 af[2], bfr[4];
#pragma unroll
    for (int m = 0; m < 2; ++m) {
      const int row = wm + m * 16 + l15;
      af[m] = *reinterpret_cast<const bf16x8*>(
          Ac + row * 64 + ((lhi * 16) ^ (((row >> 2) & 3) << 4)));
    }
#pragma unroll
    for (int n = 0; n < 4; ++n) {
      const int row = wn + n * 16 + l15;
      bfr[n] = *reinterpret_cast<const bf16x8*>(
          Bc + row * 64 + ((lhi * 16) ^ (((row >> 2) & 3) << 4)));
    }
    __builtin_amdgcn_s_setprio(1);
#pragma unroll
    for (int m = 0; m < 2; ++m)
#pragma unroll
      for (int n = 0; n < 4; ++n) acc[m][n] = mfma16(af[m], bfr[n], acc[m][n]);
    __builtin_amdgcn_s_setprio(0);
    if (kt + 1 < nt) {
      if (kt + 3 < nt)
        asm volatile("s_waitcnt vmcnt(6)" ::: "memory");  // t+1 landed
      else if (kt + 2 < nt)
        asm volatile("s_waitcnt vmcnt(3)" ::: "memory");  // drain tail
      else
        asm volatile("s_waitcnt vmcnt(0)" ::: "memory");
      __builtin_amdgcn_s_barrier();
    }
  }
#undef GEMM_STAGE

#pragma unroll
  for (int m = 0; m < 2; ++m) {
    const int row_base = m0 + wm + m * 16 + lhi * 4;
#pragma unroll
    for (int n = 0; n < 4; ++n) {
      const int col = n0 + wn + n * 16 + l15;
      const float bv = bias[col];
#pragma unroll
      for (int r = 0; r < 4; ++r) {
        const int row = row_base + r;
        float v = acc[m][n][r] + bv;
        if (RES) {
          const size_t idx = (size_t)row * N + col;
          v += RESBF ? (float)((const bf16*)res)[idx] : ((const float*)res)[idx];
        }
        if (OUT_BF16)
          ((bf16*)Cout)[(size_t)row * N + col] = (bf16)v;
        else
          ((float*)Cout)[(size_t)row * N + col] = v;
      }
    }
  }
}

// ---------------- Fused attention: QBLK=128, 8 waves (r17) ------------------
__global__ __launch_bounds__(512)
void attn_fused2(const bf16* __restrict__ Qp, const bf16* __restrict__ Kp,
                 const bf16* __restrict__ VTp, const int* __restrict__ mask,
                 float* __restrict__ probs, bf16* __restrict__ Ob) {
  constexpr int S = 2048, LD = 3072;
  __shared__ char lds[50176];  // [0,32K) K-ping(A)/Kb+Vb(B); [32K,48K) P; [48K..) msk
  const int t = threadIdx.x, wave = t >> 6, lane = t & 63;
  const int l15 = lane & 15, lhi = lane >> 4;
  const int flat = blockIdx.x + 16 * (blockIdx.y + 16 * blockIdx.z);
  const int wg = (flat & 7) * 64 + (flat >> 3);
  const int q0 = (wg & 15) * 128, h = (wg >> 4) & 15, b = wg >> 8;
  const int* mrow = mask + b * S;
  const f32x4 z4 = {0.f, 0.f, 0.f, 0.f};
  float* mskA = (float*)(lds + 49152);  // [2][128] (pass B: [2][64])

  const bf16* kgpA[2];
  int soffA[2];
#pragma unroll
  for (int i = 0; i < 2; ++i) {
    const int off = (i * 8 + wave) * 1024 + lane * 16;
    soffA[i] = off;
    const int krow = off >> 7, kbin = off & 127;
    kgpA[i] = Kp + (size_t)(b * S + krow) * LD + h * 64 + ((kbin ^ ((krow & 7) << 4)) >> 1);
  }

  bf16x8 qf[2];
#pragma unroll
  for (int ks = 0; ks < 2; ++ks)
    qf[ks] = *reinterpret_cast<const bf16x8*>(
        Qp + (size_t)(b * S + q0 + wave * 16 + l15) * LD + h * 64 + ks * 32 + lhi * 8);

  // ================= pass A: l = sum over kv of exp2(s), KB=128 =============
  bf16x8 kreg[2];
  float mnext;
#pragma unroll
  for (int i = 0; i < 2; ++i) kreg[i] = *reinterpret_cast<const bf16x8*>(kgpA[i]);
  mnext = (t < 128) ? (mrow[t] ? 0.f : 1.f) : 0.f;
#pragma unroll
  for (int i = 0; i < 2; ++i)
    *reinterpret_cast<bf16x8*>(lds + soffA[i]) = kreg[i];
  if (t < 128) mskA[t] = mnext;
  __syncthreads();

  float lpart = 0.f;
  for (int kt = 0; kt < 16; ++kt) {
    const int kv0 = kt * 128;
    if (kt + 1 < 16) {  // issue-early
#pragma unroll
      for (int i = 0; i < 2; ++i)
        kreg[i] = *reinterpret_cast<const bf16x8*>(kgpA[i] + (size_t)(kv0 + 128) * LD);
      mnext = (t < 128) ? (mrow[kv0 + 128 + t] ? 0.f : 1.f) : 0.f;
    }
    const char* kb = lds + (kt & 1) * 16384;
    const float* mc = mskA + (kt & 1) * 128;
#pragma unroll
    for (int g = 0; g < 2; ++g) {
      f32x4 sa[4];
#pragma unroll
      for (int n = 0; n < 4; ++n) sa[n] = z4;
      __builtin_amdgcn_s_setprio(1);
#pragma unroll
      for (int ks = 0; ks < 2; ++ks)
#pragma unroll
        for (int n = 0; n < 4; ++n) {
          const int krow = g * 64 + n * 16 + l15;
          bf16x8 kf = *reinterpret_cast<const bf16x8*>(
              kb + krow * 128 + ((ks * 64 + lhi * 16) ^ ((krow & 7) << 4)));
          sa[n] = mfma16(kf, qf[ks], sa[n]);
        }
      __builtin_amdgcn_s_setprio(0);
#pragma unroll
      for (int n = 0; n < 4; ++n)
#pragma unroll
        for (int r = 0; r < 4; ++r)
          lpart += __builtin_exp2f(sa[n][r]) * mc[g * 64 + n * 16 + lhi * 4 + r];
    }
    if (kt + 1 < 16) {  // write-late into the OTHER region
      char* kbn = lds + ((kt + 1) & 1) * 16384;
#pragma unroll
      for (int i = 0; i < 2; ++i)
        *reinterpret_cast<bf16x8*>(kbn + soffA[i]) = kreg[i];
      if (t < 128) mskA[((kt + 1) & 1) * 128 + t] = mnext;
    }
    __syncthreads();
  }
  lpart += __shfl_xor(lpart, 16);
  lpart += __shfl_xor(lpart, 32);
  const float il = 1.f / lpart;

  // ================= pass B: probs + PV, KB=64, 1 barrier/tile ==============
  const int offB = t * 16;
  const int krB = offB >> 7, binB = offB & 127;
  const int swB = (binB ^ ((krB & 7) << 4)) >> 1;
  const bf16* kgpB = Kp + (size_t)(b * S + krB) * LD + h * 64 + swB;
  const bf16* vgpB = VTp + (size_t)((b * 16 + h) * 64 + krB) * S + swB;
  char* Pb = lds + 32768;

  f32x4 oa[4];
#pragma unroll
  for (int n = 0; n < 4; ++n) oa[n] = z4;
  float* pbase = probs + ((size_t)(b * 16 + h) * S + q0 + wave * 16 + l15) * S;
  const int prw = wave * 16 + l15;
  const int swzp = (prw & 7) << 4;

  bf16x8 krg = *reinterpret_cast<const bf16x8*>(kgpB);
  bf16x8 vrg = *reinterpret_cast<const bf16x8*>(vgpB);
  float mnb = (t < 64) ? (mrow[t] ? 0.f : 1.f) : 0.f;
  *reinterpret_cast<bf16x8*>(lds + offB) = krg;          // Kb[0]
  *reinterpret_cast<bf16x8*>(lds + 16384 + offB) = vrg;  // Vb[0]
  if (t < 64) mskA[t] = mnb;
  __syncthreads();

  for (int kt = 0; kt < 32; ++kt) {
    const int kv0 = kt * 64;
    if (kt + 1 < 32) {  // issue-early
      krg = *reinterpret_cast<const bf16x8*>(kgpB + (size_t)(kv0 + 64) * LD);
      vrg = *reinterpret_cast<const bf16x8*>(vgpB + kv0 + 64);
      mnb = (t < 64) ? (mrow[kv0 + 64 + t] ? 0.f : 1.f) : 0.f;
    }
    const char* kc = lds + (kt & 1) * 8192;
    const char* vc = lds + 16384 + (kt & 1) * 8192;
    const float* mc = mskA + (kt & 1) * 64;

    f32x4 sa[4];
#pragma unroll
    for (int n = 0; n < 4; ++n) sa[n] = z4;
    __builtin_amdgcn_s_setprio(1);
#pragma unroll
    for (int ks = 0; ks < 2; ++ks)
#pragma unroll
      for (int n = 0; n < 4; ++n) {
        const int krow = n * 16 + l15;
        bf16x8 kf = *reinterpret_cast<const bf16x8*>(
            kc + krow * 128 + ((ks * 64 + lhi * 16) ^ ((krow & 7) << 4)));
        sa[n] = mfma16(kf, qf[ks], sa[n]);
      }
    __builtin_amdgcn_s_setprio(0);

#pragma unroll
    for (int n = 0; n < 4; ++n) {
      f32x4 praw, pn;
#pragma unroll
      for (int r = 0; r < 4; ++r) {
        praw[r] = __builtin_exp2f(sa[n][r]) * mc[n * 16 + lhi * 4 + r];
        pn[r] = praw[r] * il;
      }
      __builtin_nontemporal_store(pn, reinterpret_cast<f32x4*>(pbase + kv0 + n * 16 + lhi * 4));
      bf16x4 pb;
      pb[0] = (bf16)praw[0]; pb[1] = (bf16)praw[1];
      pb[2] = (bf16)praw[2]; pb[3] = (bf16)praw[3];
      *reinterpret_cast<bf16x4*>(Pb + prw * 128 + ((n * 32 + lhi * 8) ^ swzp)) = pb;
    }
    __builtin_amdgcn_s_setprio(1);
#pragma unroll
    for (int ks = 0; ks < 2; ++ks) {
      bf16x8 pf = *reinterpret_cast<const bf16x8*>(
          Pb + prw * 128 + ((ks * 64 + lhi * 16) ^ swzp));
#pragma unroll
      for (int nn = 0; nn < 4; ++nn) {
        const int vr = nn * 16 + l15;
        bf16x8 vf = *reinterpret_cast<const bf16x8*>(
            vc + vr * 128 + ((ks * 64 + lhi * 16) ^ ((vr & 7) << 4)));
        oa[nn] = mfma16(pf, vf, oa[nn]);
      }
    }
    __builtin_amdgcn_s_setprio(0);
    if (kt + 1 < 32) {  // write-late into the OTHER buffers
      *reinterpret_cast<bf16x8*>(lds + ((kt + 1) & 1) * 8192 + offB) = krg;
      *reinterpret_cast<bf16x8*>(lds + 16384 + ((kt + 1) & 1) * 8192 + offB) = vrg;
      if (t < 64) mskA[((kt + 1) & 1) * 64 + t] = mnb;
    }
    __syncthreads();
  }

  float il4[4];
#pragma unroll
  for (int r = 0; r < 4; ++r) il4[r] = __shfl(il, lhi * 4 + r);
#pragma unroll
  for (int nn = 0; nn < 4; ++nn)
#pragma unroll
    for (int r = 0; r < 4; ++r)
      Ob[(size_t)(b * S + q0 + wave * 16 + lhi * 4 + r) * 1024 + h * 64 + nn * 16 + l15] =
          (bf16)(oa[nn][r] * il4[r]);
}

// ---------------- launch ----------------
extern "C" void kernel_launch(void* const* d_in, const int* in_sizes, int n_in,
                              void* d_out, int out_size, void* d_ws, size_t ws_size,
                              hipStream_t stream) {
  const float* src = (const float*)d_in[0];
  const int* mask = (const int*)d_in[1];
  const float* Wq = (const float*)d_in[2];
  const float* bq = (const float*)d_in[3];
  const float* Wk = (const float*)d_in[4];
  const float* bk = (const float*)d_in[5];
  const float* Wv = (const float*)d_in[6];
  const float* bv = (const float*)d_in[7];
  const float* Wo = (const float*)d_in[8];
  const float* bo = (const float*)d_in[9];
  const float* W1 = (const float*)d_in[10];
  const float* b1 = (const float*)d_in[11];
  const float* W2 = (const float*)d_in[12];
  const float* b2 = (const float*)d_in[13];
  const float* ln1g = (const float*)d_in[14];
  const float* ln1b = (const float*)d_in[15];
  const float* ln2g = (const float*)d_in[16];
  const float* ln2b = (const float*)d_in[17];

  float* out0 = (float*)d_out;                       // [2,2048,1024]
  float* probs = (float*)d_out + (size_t)4194304;    // [2,16,2048,2048]

  char* w = (char*)d_ws;
  const size_t MB = 1u << 20;
  bf16* wqkv = (bf16*)(w);              // [3072,1024] rows: Wq|Wk|Wv (6MB)
  bf16* wob = (bf16*)(w + 6 * MB);      // [1024,1024]
  bf16* w1b = (bf16*)(w + 8 * MB);      // [4096,1024]
  bf16* w2b = (bf16*)(w + 16 * MB);     // [1024,4096]
  bf16* xn = (bf16*)(w + 24 * MB);      // [4096,1024]
  bf16* QKV = (bf16*)(w + 32 * MB);     // [4096,3072] (24MB; V cols unused)
  bf16* Ob = (bf16*)(w + 56 * MB);      // [4096,1024]
  bf16* hb = (bf16*)(w + 32 * MB);      // [4096,4096] reuse (QKV dead by then)
  bf16* VT = (bf16*)(w + 64 * MB);      // [2,16,64,2048] (8MB); dead after attn
  bf16* s2 = (bf16*)(w + 72 * MB);      // [4096,1024] bf16 (8MB)
  float* bqkv = (float*)(w + 80 * MB);  // [3072]

  // prep: weight conversion + bias concat + LN1 (1 launch)
  prep<<<16387, 256, 0, stream>>>(Wq, Wk, Wv, Wo, W1, W2, bq, bk, bv,
                                  wqkv, wob, w1b, w2b, bqkv,
                                  src, ln1g, ln1b, xn);
  // fused QKV projection (Q pre-scaled by 0.125*log2e; V written transposed to VT)
  gemm_bt3<false, true, true><<<dim3(12, 32), 512, 0, stream>>>(
      xn, wqkv, bqkv, QKV, VT, 4096, 3072, 1024);
  // fused attention (QBLK=128, 8 waves; pass B single-barrier KB=64)
  attn_fused2<<<dim3(16, 16, 2), 512, 0, stream>>>(
      QKV, QKV + 1024, VT, mask, probs, Ob);
  // Wo + residual(src fp32) -> s2 (bf16): 64x128 tile, 512 blocks, depth-3
  gemm_bt<true, true, false><<<dim3(8, 64), 256, 0, stream>>>(
      Ob, wob, bo, src, s2, 4096, 1024, 1024);
  // LN2 (bf16 input)
  ln_bf<<<4096, 256, 0, stream>>>(s2, ln2g, ln2b, xn);
  // FFN1 + ReLU: v3
  gemm_bt3<true, false, false><<<dim3(16, 32), 512, 0, stream>>>(
      xn, w1b, b1, hb, nullptr, 4096, 4096, 1024);
  // FFN2 + residual(s2 bf16) -> out0 (fp32): 64x128 tile, 512 blocks, depth-3
  gemm_bt<false, true, true><<<dim3(8, 64), 256, 0, stream>>>(
      hb, w2b, b2, s2, out0, 4096, 1024, 4096);

  (void)in_sizes; (void)n_in; (void)out_size; (void)ws_size;
}